// Round 6
// baseline (191.017 us; speedup 1.0000x reference)
//
#include <hip/hip_runtime.h>
#include <math.h>

#define TB 16
#define TL 8192
#define TC 64

constexpr float INV_BL = 1.0f / (16.0f * 8192.0f);
constexpr float EPSV = 1e-5f;
constexpr float INV_SQRT_H = 0.17677669529663687f; // 1/sqrt(32)

// workspace offsets (floats) — unchanged
#define WS_G      0        /* [16][64][64] */
#define WS_SX     65536    /* [16][64] */
#define WS_STATS  66560    /* s1[64] d1[64] s2[64] d2[64] */
#define WS_M      66816    /* [16][64][64] */
#define WS_N      132352   /* [16][64][64] */
#define WS_MPART  197888   /* [16][4][4096] -> ends 460032 */
#define WS_PT     460032   /* attn^T [16][256][256] -> ends 1508608 (overlays GPART) */
#define WS_GPART  460032   /* K1 out: [16][16][4096] -> ends 1508608 */
#define WS_SXPART 1508608  /* [16][16][64] -> ends 1524992 */
#define WS_V1     1524992  /* [16][256][64] -> ends 1787136 */
#define WS_S1T    1787136  /* [16][64][256] -> ends 2049280 */

__device__ __forceinline__ int gsw(int i, int j){
  return i*64 + ((((j>>2) ^ (i&15))<<2) | (j&3));
}

// ---------------- K1: Gram partials + row sums (v3: [l][c] stride-65, b128 frags) ----------------
// grid (16 chunk, 16 b), 512 threads = 8 waves. Tile 64 l x 64 c, double-buffered.
__global__ __launch_bounds__(512) void k1_gram(const float* __restrict__ x,
                                               float* __restrict__ ws){
  __shared__ float xt[2][64*65];
  __shared__ float gl[2][4096];
  const int b = blockIdx.y, chunk = blockIdx.x;
  const int t = threadIdx.x;
  const int w = __builtin_amdgcn_readfirstlane(t >> 6);  // wave 0..7
  const int lane = t & 63;
  const int ti = (lane>>3)&7, tj = lane&7;
  // staging: wave w stages channels cA=8w+(lane>>4), cB=cA+4; l-slice 4m..4m+3
  const int m  = lane & 15;
  const int cA = 8*w + (lane>>4);
  const int cB = cA + 4;
  float acc[8][8];
  #pragma unroll
  for (int u=0;u<8;++u)
    #pragma unroll
    for (int v=0;v<8;++v) acc[u][v]=0.f;
  float sxA = 0.f, sxB = 0.f;
  {
    float* glf = &gl[0][0];
    #pragma unroll
    for (int r=0;r<16;++r) glf[t + 512*r] = 0.f;
  }
  const float* xb = x + b*TC*TL + chunk*512;
  // stage tile 0
  {
    const float4 a0 = *(const float4*)(xb + cA*TL + 4*m);
    const float4 a1 = *(const float4*)(xb + cB*TL + 4*m);
    sxA += a0.x+a0.y+a0.z+a0.w;
    sxB += a1.x+a1.y+a1.z+a1.w;
    xt[0][(4*m+0)*65 + cA] = a0.x;
    xt[0][(4*m+1)*65 + cA] = a0.y;
    xt[0][(4*m+2)*65 + cA] = a0.z;
    xt[0][(4*m+3)*65 + cA] = a0.w;
    xt[0][(4*m+0)*65 + cB] = a1.x;
    xt[0][(4*m+1)*65 + cB] = a1.y;
    xt[0][(4*m+2)*65 + cB] = a1.z;
    xt[0][(4*m+3)*65 + cB] = a1.w;
  }
  __syncthreads();
  int buf = 0;
  for (int tile=0; tile<8; ++tile){
    float4 b0, b1;
    const bool pf = (tile < 7);
    if (pf){
      const int l0n = (tile+1)*64;
      b0 = *(const float4*)(xb + cA*TL + l0n + 4*m);
      b1 = *(const float4*)(xb + cB*TL + l0n + 4*m);
    }
    // compute: wave w handles local l = 8w..8w+7
    #pragma unroll
    for (int k=0;k<8;++k){
      const int l = 8*w + k;
      const float4 xi0 = *(const float4*)&xt[buf][l*65 + 8*ti];
      const float4 xi1 = *(const float4*)&xt[buf][l*65 + 8*ti + 4];
      const float4 xj0 = *(const float4*)&xt[buf][l*65 + 8*tj];
      const float4 xj1 = *(const float4*)&xt[buf][l*65 + 8*tj + 4];
      const float xi[8] = {xi0.x,xi0.y,xi0.z,xi0.w, xi1.x,xi1.y,xi1.z,xi1.w};
      const float xj[8] = {xj0.x,xj0.y,xj0.z,xj0.w, xj1.x,xj1.y,xj1.z,xj1.w};
      #pragma unroll
      for (int u=0;u<8;++u)
        #pragma unroll
        for (int v=0;v<8;++v)
          acc[u][v] = fmaf(xi[u], xj[v], acc[u][v]);
    }
    if (pf){
      sxA += b0.x+b0.y+b0.z+b0.w;
      sxB += b1.x+b1.y+b1.z+b1.w;
      float* xn = &xt[buf^1][0];
      xn[(4*m+0)*65 + cA] = b0.x;
      xn[(4*m+1)*65 + cA] = b0.y;
      xn[(4*m+2)*65 + cA] = b0.z;
      xn[(4*m+3)*65 + cA] = b0.w;
      xn[(4*m+0)*65 + cB] = b1.x;
      xn[(4*m+1)*65 + cB] = b1.y;
      xn[(4*m+2)*65 + cB] = b1.z;
      xn[(4*m+3)*65 + cB] = b1.w;
    }
    __syncthreads();
    buf ^= 1;
  }
  // reduce per-wave acc into 2 gl copies; wave-staggered u order -> ~2-way
  {
    float* g = &gl[w&1][0];
    #pragma unroll
    for (int uu=0;uu<8;++uu){
      const int u = (uu + w) & 7;
      #pragma unroll
      for (int v=0;v<8;++v)
        atomicAdd(&g[gsw(8*ti+u, 8*tj+v)], acc[u][v]);
    }
  }
  __syncthreads();
  float* Gp = ws + WS_GPART + (b*16 + chunk)*4096;
  #pragma unroll
  for (int r=0;r<8;++r){
    const int e = t + 512*r;
    const int s = gsw(e>>6, e&63);
    Gp[e] = gl[0][s] + gl[1][s];
  }
  // Sx: reduce over the 16 m-lanes sharing each channel
  #pragma unroll
  for (int off=1; off<16; off<<=1){
    sxA += __shfl_xor(sxA, off, 16);
    sxB += __shfl_xor(sxB, off, 16);
  }
  if (m==0){
    float* Sp = ws + WS_SXPART + (b*16+chunk)*64;
    Sp[cA] = sxA;
    Sp[cB] = sxB;
  }
}

// ---------------- KA: reduce G/Sx partials, zero stats ----------------
__global__ __launch_bounds__(256) void ka_reduce(float* __restrict__ ws){
  const int b = blockIdx.y, ig = blockIdx.x;
  const int t = threadIdx.x;
  const int base = ig*1024;
  float s[4] = {0.f,0.f,0.f,0.f};
  const float* Gp = ws + WS_GPART + b*16*4096 + base;
  #pragma unroll 4
  for (int ch=0; ch<16; ++ch){
    #pragma unroll
    for (int r=0;r<4;++r) s[r] += Gp[ch*4096 + t + 256*r];
  }
  #pragma unroll
  for (int r=0;r<4;++r) ws[WS_G + b*4096 + base + t + 256*r] = s[r];
  if (ig==0){
    if (t<64){
      float sv = 0.f;
      #pragma unroll 4
      for (int ch=0; ch<16; ++ch) sv += ws[WS_SXPART + (b*16+ch)*64 + t];
      ws[WS_SX + b*64 + t] = sv;
    }
    if (b==0) ws[WS_STATS + t] = 0.f;
  }
}

// ---------------- KA2: S1^T = (wq G)^T ----------------
__global__ __launch_bounds__(256) void ka2_s1t(const float* __restrict__ wq,
                                               float* __restrict__ ws){
  __shared__ float Gt[64*68];
  const int b = blockIdx.y, iblk = blockIdx.x;
  const int t = threadIdx.x;
  const float* G = ws + WS_G + b*4096;
  #pragma unroll
  for (int r=0;r<4;++r){
    const int idx = r*1024 + t*4;
    *(float4*)&Gt[(idx>>6)*68 + (idx&63)] = *(const float4*)(G + idx);
  }
  __syncthreads();
  const int il = t>>2, cq = t&3;
  const int i = iblk*64 + il;
  const float* wqr = wq + i*64;
  float4 a0={0,0,0,0}, a1={0,0,0,0}, a2={0,0,0,0}, a3={0,0,0,0};
  #pragma unroll 8
  for (int k=0;k<64;++k){
    const float a = wqr[k];
    const float4 g0 = *(const float4*)&Gt[k*68 + cq*16 + 0];
    const float4 g1 = *(const float4*)&Gt[k*68 + cq*16 + 4];
    const float4 g2 = *(const float4*)&Gt[k*68 + cq*16 + 8];
    const float4 g3 = *(const float4*)&Gt[k*68 + cq*16 + 12];
    a0.x=fmaf(a,g0.x,a0.x); a0.y=fmaf(a,g0.y,a0.y); a0.z=fmaf(a,g0.z,a0.z); a0.w=fmaf(a,g0.w,a0.w);
    a1.x=fmaf(a,g1.x,a1.x); a1.y=fmaf(a,g1.y,a1.y); a1.z=fmaf(a,g1.z,a1.z); a1.w=fmaf(a,g1.w,a1.w);
    a2.x=fmaf(a,g2.x,a2.x); a2.y=fmaf(a,g2.y,a2.y); a2.z=fmaf(a,g2.z,a2.z); a2.w=fmaf(a,g2.w,a2.w);
    a3.x=fmaf(a,g3.x,a3.x); a3.y=fmaf(a,g3.y,a3.y); a3.z=fmaf(a,g3.z,a3.z); a3.w=fmaf(a,g3.w,a3.w);
  }
  float* S1T = ws + WS_S1T + b*16384;
  const int c0 = cq*16;
  S1T[(c0+ 0)*256 + i]=a0.x; S1T[(c0+ 1)*256 + i]=a0.y; S1T[(c0+ 2)*256 + i]=a0.z; S1T[(c0+ 3)*256 + i]=a0.w;
  S1T[(c0+ 4)*256 + i]=a1.x; S1T[(c0+ 5)*256 + i]=a1.y; S1T[(c0+ 6)*256 + i]=a1.z; S1T[(c0+ 7)*256 + i]=a1.w;
  S1T[(c0+ 8)*256 + i]=a2.x; S1T[(c0+ 9)*256 + i]=a2.y; S1T[(c0+10)*256 + i]=a2.z; S1T[(c0+11)*256 + i]=a2.w;
  S1T[(c0+12)*256 + i]=a3.x; S1T[(c0+13)*256 + i]=a3.y; S1T[(c0+14)*256 + i]=a3.z; S1T[(c0+15)*256 + i]=a3.w;
}

// ---------------- KB1: scores + column softmax -> P^T (global) ----------------
__global__ __launch_bounds__(256) void kb1_scores(const float* __restrict__ wk,
                                                  float* __restrict__ ws){
  __shared__ float scl[256*17];
  __shared__ float pstat[256];
  __shared__ float fstat[32];
  const int b = blockIdx.y, jp = blockIdx.x;
  const int j0 = jp*16;
  const int t = threadIdx.x;
  const float* S1Tb = ws + WS_S1T + b*16384;
  float sc[16];
  #pragma unroll
  for (int jj=0;jj<16;++jj) sc[jj]=0.f;
  #pragma unroll 2
  for (int k=0;k<64;++k){
    const float s1 = S1Tb[k*256 + t];
    const float* wkr = wk + j0*64 + k;
    #pragma unroll
    for (int jj=0;jj<16;++jj)
      sc[jj] = fmaf(wkr[jj*64], s1, sc[jj]);
  }
  #pragma unroll
  for (int jj=0;jj<16;++jj) scl[t*17+jj] = sc[jj];
  __syncthreads();
  const int col = t&15, ig = t>>4;
  {
    float m = -3.0e38f;
    #pragma unroll
    for (int q=0;q<16;++q) m = fmaxf(m, scl[(ig*16+q)*17 + col]);
    pstat[ig*16+col] = m;
  }
  __syncthreads();
  if (t<16){
    float m = -3.0e38f;
    #pragma unroll
    for (int q=0;q<16;++q) m = fmaxf(m, pstat[q*16+t]);
    fstat[t] = m;
  }
  __syncthreads();
  {
    const float mj = fstat[col];
    float s = 0.f;
    #pragma unroll
    for (int q=0;q<16;++q) s += __expf(scl[(ig*16+q)*17 + col] - mj);
    pstat[ig*16+col] = s;
  }
  __syncthreads();
  if (t<16){
    float s = 0.f;
    #pragma unroll
    for (int q=0;q<16;++q) s += pstat[q*16+t];
    fstat[16+t] = 1.f/s;
  }
  __syncthreads();
  float* PTb = ws + WS_PT + b*65536;
  #pragma unroll
  for (int jj=0;jj<16;++jj){
    const float p = __expf(sc[jj] - fstat[jj]) * fstat[16+jj];
    PTb[(j0+jj)*256 + t] = p;
  }
}

// ---------------- KB2: V1 = (P wv) * 1/sqrt(H) ----------------
__global__ __launch_bounds__(256) void kb2_v1(const float* __restrict__ wv,
                                              float* __restrict__ ws){
  __shared__ float PTl[64*65];
  const int b = blockIdx.y, iq = blockIdx.x;
  const int t = threadIdx.x;
  const int i = t&63;
  const int cg = __builtin_amdgcn_readfirstlane(t>>6);
  float acc[16];
  #pragma unroll
  for (int cc=0;cc<16;++cc) acc[cc]=0.f;
  const float* PTb = ws + WS_PT + b*65536 + iq*64;
  for (int jc=0;jc<4;++jc){
    __syncthreads();
    #pragma unroll
    for (int r=0;r<16;++r){
      const int e = t + 256*r;
      PTl[(e>>6)*65 + (e&63)] = PTb[(jc*64 + (e>>6))*256 + (e&63)];
    }
    __syncthreads();
    #pragma unroll 4
    for (int jj=0;jj<64;++jj){
      const float p = PTl[jj*65 + i];
      const float* wvr = wv + (jc*64+jj)*64 + cg*16;
      #pragma unroll
      for (int cc=0;cc<16;++cc)
        acc[cc] = fmaf(p, wvr[cc], acc[cc]);
    }
  }
  float* V1o = ws + WS_V1 + b*16384 + (iq*64+i)*64 + cg*16;
  #pragma unroll
  for (int cc=0;cc<16;++cc) V1o[cc] = acc[cc]*INV_SQRT_H;
}

// ---------------- KC: M K-partials = wc-slice @ V1-slice ----------------
__global__ __launch_bounds__(256) void kc_mpart(const float* __restrict__ wc,
                                                float* __restrict__ ws){
  __shared__ float V1l[4096];
  const int b = blockIdx.y, kq = blockIdx.x;
  const int t = threadIdx.x;
  const float* Vsrc = ws + WS_V1 + b*16384 + kq*4096;
  #pragma unroll
  for (int r=0;r<16;++r) V1l[t + 256*r] = Vsrc[t + 256*r];
  __syncthreads();
  const int c = t&63;
  const int og = __builtin_amdgcn_readfirstlane(t>>6);
  float acc[16];
  #pragma unroll
  for (int oo=0;oo<16;++oo) acc[oo]=0.f;
  #pragma unroll 4
  for (int i=0;i<64;++i){
    const float v = V1l[i*64 + c];
    const float* wcr = wc + (og*16)*256 + kq*64 + i;
    #pragma unroll
    for (int oo=0;oo<16;++oo)
      acc[oo] = fmaf(wcr[oo*256], v, acc[oo]);
  }
  float* Mp = ws + WS_MPART + (b*4 + kq)*4096;
  #pragma unroll
  for (int oo=0;oo<16;++oo)
    Mp[(og*16+oo)*64 + c] = acc[oo];
}

// ---------------- KD: M rows + BN1 stats partials ----------------
__global__ __launch_bounds__(256) void kd_stats1(float* __restrict__ ws){
  __shared__ float Msub[16*65];
  __shared__ float Gl[64*67];
  __shared__ float Sxl[64];
  const int b = blockIdx.y, oq = blockIdx.x;
  const int t = threadIdx.x;
  const float* Mp = ws + WS_MPART + b*4*4096 + oq*1024;
  #pragma unroll
  for (int r=0;r<4;++r){
    const int e = t + 256*r;
    const float s = Mp[e] + Mp[4096+e] + Mp[2*4096+e] + Mp[3*4096+e];
    ws[WS_M + b*4096 + oq*1024 + e] = s;
    Msub[(e>>6)*65 + (e&63)] = s;
  }
  #pragma unroll 4
  for (int r=0;r<16;++r){
    const int e = t + 256*r;
    Gl[(e>>6)*67 + (e&63)] = ws[WS_G + b*4096 + e];
  }
  if (t<64) Sxl[t] = ws[WS_SX + b*64 + t];
  __syncthreads();
  const int o = t>>4, q = t&15;
  float d = 0.f;
  #pragma unroll
  for (int kk=0;kk<4;++kk){
    const int k = q*4+kk;
    float s = 0.f;
    #pragma unroll 4
    for (int c=0;c<64;++c) s = fmaf(Gl[k*67+c], Msub[o*65+c], s);
    d = fmaf(Msub[o*65+k], s, d);
  }
  d += __shfl_xor(d, 1, 16);
  d += __shfl_xor(d, 2, 16);
  d += __shfl_xor(d, 4, 16);
  d += __shfl_xor(d, 8, 16);
  if (q==0){
    float s1 = 0.f;
    #pragma unroll 4
    for (int c=0;c<64;++c) s1 = fmaf(Msub[o*65+c], Sxl[c], s1);
    atomicAdd(&ws[WS_STATS + oq*16 + o], s1);
    atomicAdd(&ws[WS_STATS + 64 + oq*16 + o], d);
  }
}

// ---------------- KE: N rows + BN2 stats partials ----------------
__global__ __launch_bounds__(256) void ke_n_stats2(const float* __restrict__ wl,
                                                   const float* __restrict__ g1,
                                                   float* __restrict__ ws){
  __shared__ float Ml[64*65];
  __shared__ float Gl[64*67];
  __shared__ float wls[16*65];
  __shared__ float Nsub[16*65];
  __shared__ float Sxl[64], a1l[64];
  const int b = blockIdx.y, oq = blockIdx.x;
  const int t = threadIdx.x;
  if (t<64){
    const float mean1 = ws[WS_STATS+t]*INV_BL;
    const float var1 = ws[WS_STATS+64+t]*INV_BL - mean1*mean1;
    a1l[t] = g1[t]*rsqrtf(var1 + EPSV);
    Sxl[t] = ws[WS_SX + b*64 + t];
  }
  #pragma unroll 4
  for (int r=0;r<16;++r){
    const int e = t + 256*r;
    Ml[(e>>6)*65 + (e&63)] = ws[WS_M + b*4096 + e];
    Gl[(e>>6)*67 + (e&63)] = ws[WS_G + b*4096 + e];
  }
  __syncthreads();
  #pragma unroll
  for (int r=0;r<4;++r){
    const int e = t + 256*r;
    wls[(e>>6)*65 + (e&63)] = wl[(oq*16 + (e>>6))*64 + (e&63)] * a1l[e&63];
  }
  __syncthreads();
  const int o = t>>4, q = t&15;
  const int row = oq*16 + o;
  {
    float acc[4];
    #pragma unroll
    for (int cc=0;cc<4;++cc) acc[cc]=0.f;
    #pragma unroll 4
    for (int k=0;k<64;++k){
      const float w = wls[o*65 + k];
      #pragma unroll
      for (int cc=0;cc<4;++cc)
        acc[cc] = fmaf(w, Ml[k*65 + q*4 + cc], acc[cc]);
    }
    #pragma unroll
    for (int cc=0;cc<4;++cc){
      const float nv = acc[cc] + wl[row*64 + q*4 + cc];
      ws[WS_N + b*4096 + o*64 + oq*1024 + q*4 + cc] = nv;
      Nsub[o*65 + q*4 + cc] = nv;
    }
  }
  __syncthreads();
  float d = 0.f;
  #pragma unroll
  for (int kk=0;kk<4;++kk){
    const int k = q*4+kk;
    float s = 0.f;
    #pragma unroll 4
    for (int c=0;c<64;++c) s = fmaf(Gl[k*67+c], Nsub[o*65+c], s);
    d = fmaf(Nsub[o*65+k], s, d);
  }
  d += __shfl_xor(d, 1, 16);
  d += __shfl_xor(d, 2, 16);
  d += __shfl_xor(d, 4, 16);
  d += __shfl_xor(d, 8, 16);
  if (q==0){
    float s2 = 0.f;
    #pragma unroll 4
    for (int c=0;c<64;++c) s2 = fmaf(Nsub[o*65+c], Sxl[c], s2);
    atomicAdd(&ws[WS_STATS + 128 + row], s2);
    atomicAdd(&ws[WS_STATS + 192 + row], d);
  }
}

// ---------------- K3: out = relu(a2*(N x) + e) ----------------
__global__ __launch_bounds__(256) void k3_out(const float* __restrict__ x,
                                              const float* __restrict__ g2,
                                              const float* __restrict__ b2,
                                              const float* __restrict__ ws,
                                              float* __restrict__ out){
  __shared__ float a2l[64], el[64];
  const int b = blockIdx.y, lc = blockIdx.x;
  const int t = threadIdx.x;
  if (t<64){
    const float mu = ws[WS_STATS+128+t]*INV_BL;
    const float var2 = ws[WS_STATS+192+t]*INV_BL - mu*mu;
    const float a2 = g2[t]*rsqrtf(var2 + EPSV);
    a2l[t] = a2;
    el[t] = b2[t] - a2*mu;
  }
  __syncthreads();
  const int w = __builtin_amdgcn_readfirstlane(t >> 6);
  const int lane = t & 63;
  const int l = lc*256 + 4*lane;
  const float* Np = ws + WS_N + b*4096 + w*1024;
  const float* xb = x + b*TC*TL + l;
  float4 acc[16];
  #pragma unroll
  for (int oo=0;oo<16;++oo){ acc[oo].x=0.f; acc[oo].y=0.f; acc[oo].z=0.f; acc[oo].w=0.f; }
  #pragma unroll 4
  for (int c=0;c<64;++c){
    const float4 xv = *(const float4*)(xb + c*TL);
    #pragma unroll
    for (int oo=0;oo<16;++oo){
      const float nv = Np[oo*64 + c];
      acc[oo].x = fmaf(nv, xv.x, acc[oo].x);
      acc[oo].y = fmaf(nv, xv.y, acc[oo].y);
      acc[oo].z = fmaf(nv, xv.z, acc[oo].z);
      acc[oo].w = fmaf(nv, xv.w, acc[oo].w);
    }
  }
  #pragma unroll
  for (int oo=0;oo<16;++oo){
    const float a2v = a2l[w*16+oo], ev = el[w*16+oo];
    float4 r;
    r.x = fmaxf(fmaf(a2v, acc[oo].x, ev), 0.f);
    r.y = fmaxf(fmaf(a2v, acc[oo].y, ev), 0.f);
    r.z = fmaxf(fmaf(a2v, acc[oo].z, ev), 0.f);
    r.w = fmaxf(fmaf(a2v, acc[oo].w, ev), 0.f);
    *(float4*)(out + (b*TC + w*16 + oo)*TL + l) = r;
  }
}

extern "C" void kernel_launch(void* const* d_in, const int* in_sizes, int n_in,
                              void* d_out, int out_size, void* d_ws, size_t ws_size,
                              hipStream_t stream){
  const float* x  = (const float*)d_in[0];
  const float* wk = (const float*)d_in[1];
  const float* wq = (const float*)d_in[2];
  const float* wv = (const float*)d_in[3];
  const float* wc = (const float*)d_in[4];
  const float* g1 = (const float*)d_in[5];
  /* b1 (d_in[6]) provably cancels through BN2 mean-subtraction */
  const float* wl = (const float*)d_in[7];
  const float* g2 = (const float*)d_in[8];
  const float* b2 = (const float*)d_in[9];
  float* out = (float*)d_out;
  float* ws  = (float*)d_ws;

  k1_gram    <<<dim3(16,16), 512, 0, stream>>>(x, ws);
  ka_reduce  <<<dim3(4,16),  256, 0, stream>>>(ws);
  ka2_s1t    <<<dim3(4,16),  256, 0, stream>>>(wq, ws);
  kb1_scores <<<dim3(16,16), 256, 0, stream>>>(wk, ws);
  kb2_v1     <<<dim3(4,16),  256, 0, stream>>>(wv, ws);
  kc_mpart   <<<dim3(4,16),  256, 0, stream>>>(wc, ws);
  kd_stats1  <<<dim3(4,16),  256, 0, stream>>>(ws);
  ke_n_stats2<<<dim3(4,16),  256, 0, stream>>>(wl, g1, ws);
  k3_out     <<<dim3(32,16), 256, 0, stream>>>(x, g2, b2, ws, out);
}

// Round 7
// 161.322 us; speedup vs baseline: 1.1841x; 1.1841x over previous
//
#include <hip/hip_runtime.h>
#include <math.h>

#define TB 16
#define TL 8192
#define TC 64

constexpr float INV_BL = 1.0f / (16.0f * 8192.0f);
constexpr float EPSV = 1e-5f;
constexpr float INV_SQRT_H = 0.17677669529663687f; // 1/sqrt(32)

// workspace offsets (floats) — unchanged
#define WS_G      0        /* [16][64][64] */
#define WS_SX     65536    /* [16][64] */
#define WS_STATS  66560    /* s1[64] d1[64] s2[64] d2[64] */
#define WS_M      66816    /* [16][64][64] */
#define WS_N      132352   /* [16][64][64] */
#define WS_MPART  197888   /* [16][4][4096] -> ends 460032 */
#define WS_PT     460032   /* attn^T [16][256][256] -> ends 1508608 (overlays GPART) */
#define WS_GPART  460032   /* K1 out: [16][16][4096] -> ends 1508608 */
#define WS_SXPART 1508608  /* [16][16][64] -> ends 1524992 */
#define WS_V1     1524992  /* [16][256][64] -> ends 1787136 */
#define WS_S1T    1787136  /* [16][64][256] -> ends 2049280 */

__device__ __forceinline__ int gsw(int i, int j){
  return i*64 + ((((j>>2) ^ (i&15))<<2) | (j&3));
}

// ---------------- K1: Gram partials + row sums (v4 = v3 with STATIC acc indexing) ----------------
// grid (16 chunk, 16 b), 512 threads = 8 waves. Tile 64 l x 64 c, [l][c] stride 65, dbuf.
__global__ __launch_bounds__(512) void k1_gram(const float* __restrict__ x,
                                               float* __restrict__ ws){
  __shared__ float xt[2][64*65];
  __shared__ float gl[2][4096];
  const int b = blockIdx.y, chunk = blockIdx.x;
  const int t = threadIdx.x;
  const int w = __builtin_amdgcn_readfirstlane(t >> 6);  // wave 0..7
  const int lane = t & 63;
  const int ti = (lane>>3)&7, tj = lane&7;
  const int m  = lane & 15;
  const int cA = 8*w + (lane>>4);
  const int cB = cA + 4;
  float acc[8][8];
  #pragma unroll
  for (int u=0;u<8;++u)
    #pragma unroll
    for (int v=0;v<8;++v) acc[u][v]=0.f;
  float sxA = 0.f, sxB = 0.f;
  {
    float* glf = &gl[0][0];
    #pragma unroll
    for (int r=0;r<16;++r) glf[t + 512*r] = 0.f;
  }
  const float* xb = x + b*TC*TL + chunk*512;
  // stage tile 0
  {
    const float4 a0 = *(const float4*)(xb + cA*TL + 4*m);
    const float4 a1 = *(const float4*)(xb + cB*TL + 4*m);
    sxA += a0.x+a0.y+a0.z+a0.w;
    sxB += a1.x+a1.y+a1.z+a1.w;
    xt[0][(4*m+0)*65 + cA] = a0.x;
    xt[0][(4*m+1)*65 + cA] = a0.y;
    xt[0][(4*m+2)*65 + cA] = a0.z;
    xt[0][(4*m+3)*65 + cA] = a0.w;
    xt[0][(4*m+0)*65 + cB] = a1.x;
    xt[0][(4*m+1)*65 + cB] = a1.y;
    xt[0][(4*m+2)*65 + cB] = a1.z;
    xt[0][(4*m+3)*65 + cB] = a1.w;
  }
  __syncthreads();
  int buf = 0;
  for (int tile=0; tile<8; ++tile){
    float4 b0, b1;
    const bool pf = (tile < 7);
    if (pf){
      const int l0n = (tile+1)*64;
      b0 = *(const float4*)(xb + cA*TL + l0n + 4*m);
      b1 = *(const float4*)(xb + cB*TL + l0n + 4*m);
    }
    // compute: wave w handles local l = 8w..8w+7
    #pragma unroll
    for (int k=0;k<8;++k){
      const int l = 8*w + k;
      const float4 xi0 = *(const float4*)&xt[buf][l*65 + 8*ti];
      const float4 xi1 = *(const float4*)&xt[buf][l*65 + 8*ti + 4];
      const float4 xj0 = *(const float4*)&xt[buf][l*65 + 8*tj];
      const float4 xj1 = *(const float4*)&xt[buf][l*65 + 8*tj + 4];
      const float xi[8] = {xi0.x,xi0.y,xi0.z,xi0.w, xi1.x,xi1.y,xi1.z,xi1.w};
      const float xj[8] = {xj0.x,xj0.y,xj0.z,xj0.w, xj1.x,xj1.y,xj1.z,xj1.w};
      #pragma unroll
      for (int u=0;u<8;++u)
        #pragma unroll
        for (int v=0;v<8;++v)
          acc[u][v] = fmaf(xi[u], xj[v], acc[u][v]);
    }
    if (pf){
      sxA += b0.x+b0.y+b0.z+b0.w;
      sxB += b1.x+b1.y+b1.z+b1.w;
      float* xn = &xt[buf^1][0];
      xn[(4*m+0)*65 + cA] = b0.x;
      xn[(4*m+1)*65 + cA] = b0.y;
      xn[(4*m+2)*65 + cA] = b0.z;
      xn[(4*m+3)*65 + cA] = b0.w;
      xn[(4*m+0)*65 + cB] = b1.x;
      xn[(4*m+1)*65 + cB] = b1.y;
      xn[(4*m+2)*65 + cB] = b1.z;
      xn[(4*m+3)*65 + cB] = b1.w;
    }
    __syncthreads();
    buf ^= 1;
  }
  // reduce per-wave acc into 2 gl copies — STATIC indices only (rule #20)
  {
    float* g = &gl[w&1][0];
    #pragma unroll
    for (int u=0;u<8;++u)
      #pragma unroll
      for (int v=0;v<8;++v)
        atomicAdd(&g[gsw(8*ti+u, 8*tj+v)], acc[u][v]);
  }
  __syncthreads();
  float* Gp = ws + WS_GPART + (b*16 + chunk)*4096;
  #pragma unroll
  for (int r=0;r<8;++r){
    const int e = t + 512*r;
    const int s = gsw(e>>6, e&63);
    Gp[e] = gl[0][s] + gl[1][s];
  }
  // Sx: reduce over the 16 m-lanes sharing each channel
  #pragma unroll
  for (int off=1; off<16; off<<=1){
    sxA += __shfl_xor(sxA, off, 16);
    sxB += __shfl_xor(sxB, off, 16);
  }
  if (m==0){
    float* Sp = ws + WS_SXPART + (b*16+chunk)*64;
    Sp[cA] = sxA;
    Sp[cB] = sxB;
  }
}

// ---------------- KA: reduce G/Sx partials, zero stats ----------------
__global__ __launch_bounds__(256) void ka_reduce(float* __restrict__ ws){
  const int b = blockIdx.y, ig = blockIdx.x;
  const int t = threadIdx.x;
  const int base = ig*1024;
  float s[4] = {0.f,0.f,0.f,0.f};
  const float* Gp = ws + WS_GPART + b*16*4096 + base;
  #pragma unroll 4
  for (int ch=0; ch<16; ++ch){
    #pragma unroll
    for (int r=0;r<4;++r) s[r] += Gp[ch*4096 + t + 256*r];
  }
  #pragma unroll
  for (int r=0;r<4;++r) ws[WS_G + b*4096 + base + t + 256*r] = s[r];
  if (ig==0){
    if (t<64){
      float sv = 0.f;
      #pragma unroll 4
      for (int ch=0; ch<16; ++ch) sv += ws[WS_SXPART + (b*16+ch)*64 + t];
      ws[WS_SX + b*64 + t] = sv;
    }
    if (b==0) ws[WS_STATS + t] = 0.f;
  }
}

// ---------------- KA2: S1^T = (wq G)^T ----------------
__global__ __launch_bounds__(256) void ka2_s1t(const float* __restrict__ wq,
                                               float* __restrict__ ws){
  __shared__ float Gt[64*68];
  const int b = blockIdx.y, iblk = blockIdx.x;
  const int t = threadIdx.x;
  const float* G = ws + WS_G + b*4096;
  #pragma unroll
  for (int r=0;r<4;++r){
    const int idx = r*1024 + t*4;
    *(float4*)&Gt[(idx>>6)*68 + (idx&63)] = *(const float4*)(G + idx);
  }
  __syncthreads();
  const int il = t>>2, cq = t&3;
  const int i = iblk*64 + il;
  const float* wqr = wq + i*64;
  float4 a0={0,0,0,0}, a1={0,0,0,0}, a2={0,0,0,0}, a3={0,0,0,0};
  #pragma unroll 8
  for (int k=0;k<64;++k){
    const float a = wqr[k];
    const float4 g0 = *(const float4*)&Gt[k*68 + cq*16 + 0];
    const float4 g1 = *(const float4*)&Gt[k*68 + cq*16 + 4];
    const float4 g2 = *(const float4*)&Gt[k*68 + cq*16 + 8];
    const float4 g3 = *(const float4*)&Gt[k*68 + cq*16 + 12];
    a0.x=fmaf(a,g0.x,a0.x); a0.y=fmaf(a,g0.y,a0.y); a0.z=fmaf(a,g0.z,a0.z); a0.w=fmaf(a,g0.w,a0.w);
    a1.x=fmaf(a,g1.x,a1.x); a1.y=fmaf(a,g1.y,a1.y); a1.z=fmaf(a,g1.z,a1.z); a1.w=fmaf(a,g1.w,a1.w);
    a2.x=fmaf(a,g2.x,a2.x); a2.y=fmaf(a,g2.y,a2.y); a2.z=fmaf(a,g2.z,a2.z); a2.w=fmaf(a,g2.w,a2.w);
    a3.x=fmaf(a,g3.x,a3.x); a3.y=fmaf(a,g3.y,a3.y); a3.z=fmaf(a,g3.z,a3.z); a3.w=fmaf(a,g3.w,a3.w);
  }
  float* S1T = ws + WS_S1T + b*16384;
  const int c0 = cq*16;
  S1T[(c0+ 0)*256 + i]=a0.x; S1T[(c0+ 1)*256 + i]=a0.y; S1T[(c0+ 2)*256 + i]=a0.z; S1T[(c0+ 3)*256 + i]=a0.w;
  S1T[(c0+ 4)*256 + i]=a1.x; S1T[(c0+ 5)*256 + i]=a1.y; S1T[(c0+ 6)*256 + i]=a1.z; S1T[(c0+ 7)*256 + i]=a1.w;
  S1T[(c0+ 8)*256 + i]=a2.x; S1T[(c0+ 9)*256 + i]=a2.y; S1T[(c0+10)*256 + i]=a2.z; S1T[(c0+11)*256 + i]=a2.w;
  S1T[(c0+12)*256 + i]=a3.x; S1T[(c0+13)*256 + i]=a3.y; S1T[(c0+14)*256 + i]=a3.z; S1T[(c0+15)*256 + i]=a3.w;
}

// ---------------- KB1: scores + column softmax -> P^T (global) ----------------
__global__ __launch_bounds__(256) void kb1_scores(const float* __restrict__ wk,
                                                  float* __restrict__ ws){
  __shared__ float scl[256*17];
  __shared__ float pstat[256];
  __shared__ float fstat[32];
  const int b = blockIdx.y, jp = blockIdx.x;
  const int j0 = jp*16;
  const int t = threadIdx.x;
  const float* S1Tb = ws + WS_S1T + b*16384;
  float sc[16];
  #pragma unroll
  for (int jj=0;jj<16;++jj) sc[jj]=0.f;
  #pragma unroll 2
  for (int k=0;k<64;++k){
    const float s1 = S1Tb[k*256 + t];
    const float* wkr = wk + j0*64 + k;
    #pragma unroll
    for (int jj=0;jj<16;++jj)
      sc[jj] = fmaf(wkr[jj*64], s1, sc[jj]);
  }
  #pragma unroll
  for (int jj=0;jj<16;++jj) scl[t*17+jj] = sc[jj];
  __syncthreads();
  const int col = t&15, ig = t>>4;
  {
    float m = -3.0e38f;
    #pragma unroll
    for (int q=0;q<16;++q) m = fmaxf(m, scl[(ig*16+q)*17 + col]);
    pstat[ig*16+col] = m;
  }
  __syncthreads();
  if (t<16){
    float m = -3.0e38f;
    #pragma unroll
    for (int q=0;q<16;++q) m = fmaxf(m, pstat[q*16+t]);
    fstat[t] = m;
  }
  __syncthreads();
  {
    const float mj = fstat[col];
    float s = 0.f;
    #pragma unroll
    for (int q=0;q<16;++q) s += __expf(scl[(ig*16+q)*17 + col] - mj);
    pstat[ig*16+col] = s;
  }
  __syncthreads();
  if (t<16){
    float s = 0.f;
    #pragma unroll
    for (int q=0;q<16;++q) s += pstat[q*16+t];
    fstat[16+t] = 1.f/s;
  }
  __syncthreads();
  float* PTb = ws + WS_PT + b*65536;
  #pragma unroll
  for (int jj=0;jj<16;++jj){
    const float p = __expf(sc[jj] - fstat[jj]) * fstat[16+jj];
    PTb[(j0+jj)*256 + t] = p;
  }
}

// ---------------- KB2: V1 = (P wv) * 1/sqrt(H) ----------------
__global__ __launch_bounds__(256) void kb2_v1(const float* __restrict__ wv,
                                              float* __restrict__ ws){
  __shared__ float PTl[64*65];
  const int b = blockIdx.y, iq = blockIdx.x;
  const int t = threadIdx.x;
  const int i = t&63;
  const int cg = __builtin_amdgcn_readfirstlane(t>>6);
  float acc[16];
  #pragma unroll
  for (int cc=0;cc<16;++cc) acc[cc]=0.f;
  const float* PTb = ws + WS_PT + b*65536 + iq*64;
  for (int jc=0;jc<4;++jc){
    __syncthreads();
    #pragma unroll
    for (int r=0;r<16;++r){
      const int e = t + 256*r;
      PTl[(e>>6)*65 + (e&63)] = PTb[(jc*64 + (e>>6))*256 + (e&63)];
    }
    __syncthreads();
    #pragma unroll 4
    for (int jj=0;jj<64;++jj){
      const float p = PTl[jj*65 + i];
      const float* wvr = wv + (jc*64+jj)*64 + cg*16;
      #pragma unroll
      for (int cc=0;cc<16;++cc)
        acc[cc] = fmaf(p, wvr[cc], acc[cc]);
    }
  }
  float* V1o = ws + WS_V1 + b*16384 + (iq*64+i)*64 + cg*16;
  #pragma unroll
  for (int cc=0;cc<16;++cc) V1o[cc] = acc[cc]*INV_SQRT_H;
}

// ---------------- KC: M K-partials = wc-slice @ V1-slice ----------------
__global__ __launch_bounds__(256) void kc_mpart(const float* __restrict__ wc,
                                                float* __restrict__ ws){
  __shared__ float V1l[4096];
  const int b = blockIdx.y, kq = blockIdx.x;
  const int t = threadIdx.x;
  const float* Vsrc = ws + WS_V1 + b*16384 + kq*4096;
  #pragma unroll
  for (int r=0;r<16;++r) V1l[t + 256*r] = Vsrc[t + 256*r];
  __syncthreads();
  const int c = t&63;
  const int og = __builtin_amdgcn_readfirstlane(t>>6);
  float acc[16];
  #pragma unroll
  for (int oo=0;oo<16;++oo) acc[oo]=0.f;
  #pragma unroll 4
  for (int i=0;i<64;++i){
    const float v = V1l[i*64 + c];
    const float* wcr = wc + (og*16)*256 + kq*64 + i;
    #pragma unroll
    for (int oo=0;oo<16;++oo)
      acc[oo] = fmaf(wcr[oo*256], v, acc[oo]);
  }
  float* Mp = ws + WS_MPART + (b*4 + kq)*4096;
  #pragma unroll
  for (int oo=0;oo<16;++oo)
    Mp[(og*16+oo)*64 + c] = acc[oo];
}

// ---------------- KD: M rows + BN1 stats partials ----------------
__global__ __launch_bounds__(256) void kd_stats1(float* __restrict__ ws){
  __shared__ float Msub[16*65];
  __shared__ float Gl[64*67];
  __shared__ float Sxl[64];
  const int b = blockIdx.y, oq = blockIdx.x;
  const int t = threadIdx.x;
  const float* Mp = ws + WS_MPART + b*4*4096 + oq*1024;
  #pragma unroll
  for (int r=0;r<4;++r){
    const int e = t + 256*r;
    const float s = Mp[e] + Mp[4096+e] + Mp[2*4096+e] + Mp[3*4096+e];
    ws[WS_M + b*4096 + oq*1024 + e] = s;
    Msub[(e>>6)*65 + (e&63)] = s;
  }
  #pragma unroll 4
  for (int r=0;r<16;++r){
    const int e = t + 256*r;
    Gl[(e>>6)*67 + (e&63)] = ws[WS_G + b*4096 + e];
  }
  if (t<64) Sxl[t] = ws[WS_SX + b*64 + t];
  __syncthreads();
  const int o = t>>4, q = t&15;
  float d = 0.f;
  #pragma unroll
  for (int kk=0;kk<4;++kk){
    const int k = q*4+kk;
    float s = 0.f;
    #pragma unroll 4
    for (int c=0;c<64;++c) s = fmaf(Gl[k*67+c], Msub[o*65+c], s);
    d = fmaf(Msub[o*65+k], s, d);
  }
  d += __shfl_xor(d, 1, 16);
  d += __shfl_xor(d, 2, 16);
  d += __shfl_xor(d, 4, 16);
  d += __shfl_xor(d, 8, 16);
  if (q==0){
    float s1 = 0.f;
    #pragma unroll 4
    for (int c=0;c<64;++c) s1 = fmaf(Msub[o*65+c], Sxl[c], s1);
    atomicAdd(&ws[WS_STATS + oq*16 + o], s1);
    atomicAdd(&ws[WS_STATS + 64 + oq*16 + o], d);
  }
}

// ---------------- KE: N rows + BN2 stats partials ----------------
__global__ __launch_bounds__(256) void ke_n_stats2(const float* __restrict__ wl,
                                                   const float* __restrict__ g1,
                                                   float* __restrict__ ws){
  __shared__ float Ml[64*65];
  __shared__ float Gl[64*67];
  __shared__ float wls[16*65];
  __shared__ float Nsub[16*65];
  __shared__ float Sxl[64], a1l[64];
  const int b = blockIdx.y, oq = blockIdx.x;
  const int t = threadIdx.x;
  if (t<64){
    const float mean1 = ws[WS_STATS+t]*INV_BL;
    const float var1 = ws[WS_STATS+64+t]*INV_BL - mean1*mean1;
    a1l[t] = g1[t]*rsqrtf(var1 + EPSV);
    Sxl[t] = ws[WS_SX + b*64 + t];
  }
  #pragma unroll 4
  for (int r=0;r<16;++r){
    const int e = t + 256*r;
    Ml[(e>>6)*65 + (e&63)] = ws[WS_M + b*4096 + e];
    Gl[(e>>6)*67 + (e&63)] = ws[WS_G + b*4096 + e];
  }
  __syncthreads();
  #pragma unroll
  for (int r=0;r<4;++r){
    const int e = t + 256*r;
    wls[(e>>6)*65 + (e&63)] = wl[(oq*16 + (e>>6))*64 + (e&63)] * a1l[e&63];
  }
  __syncthreads();
  const int o = t>>4, q = t&15;
  const int row = oq*16 + o;
  {
    float acc[4];
    #pragma unroll
    for (int cc=0;cc<4;++cc) acc[cc]=0.f;
    #pragma unroll 4
    for (int k=0;k<64;++k){
      const float w = wls[o*65 + k];
      #pragma unroll
      for (int cc=0;cc<4;++cc)
        acc[cc] = fmaf(w, Ml[k*65 + q*4 + cc], acc[cc]);
    }
    #pragma unroll
    for (int cc=0;cc<4;++cc){
      const float nv = acc[cc] + wl[row*64 + q*4 + cc];
      ws[WS_N + b*4096 + o*64 + oq*1024 + q*4 + cc] = nv;
      Nsub[o*65 + q*4 + cc] = nv;
    }
  }
  __syncthreads();
  float d = 0.f;
  #pragma unroll
  for (int kk=0;kk<4;++kk){
    const int k = q*4+kk;
    float s = 0.f;
    #pragma unroll 4
    for (int c=0;c<64;++c) s = fmaf(Gl[k*67+c], Nsub[o*65+c], s);
    d = fmaf(Nsub[o*65+k], s, d);
  }
  d += __shfl_xor(d, 1, 16);
  d += __shfl_xor(d, 2, 16);
  d += __shfl_xor(d, 4, 16);
  d += __shfl_xor(d, 8, 16);
  if (q==0){
    float s2 = 0.f;
    #pragma unroll 4
    for (int c=0;c<64;++c) s2 = fmaf(Nsub[o*65+c], Sxl[c], s2);
    atomicAdd(&ws[WS_STATS + 128 + row], s2);
    atomicAdd(&ws[WS_STATS + 192 + row], d);
  }
}

// ---------------- K3: out = relu(a2*(N x) + e) ----------------
__global__ __launch_bounds__(256) void k3_out(const float* __restrict__ x,
                                              const float* __restrict__ g2,
                                              const float* __restrict__ b2,
                                              const float* __restrict__ ws,
                                              float* __restrict__ out){
  __shared__ float a2l[64], el[64];
  const int b = blockIdx.y, lc = blockIdx.x;
  const int t = threadIdx.x;
  if (t<64){
    const float mu = ws[WS_STATS+128+t]*INV_BL;
    const float var2 = ws[WS_STATS+192+t]*INV_BL - mu*mu;
    const float a2 = g2[t]*rsqrtf(var2 + EPSV);
    a2l[t] = a2;
    el[t] = b2[t] - a2*mu;
  }
  __syncthreads();
  const int w = __builtin_amdgcn_readfirstlane(t >> 6);
  const int lane = t & 63;
  const int l = lc*256 + 4*lane;
  const float* Np = ws + WS_N + b*4096 + w*1024;
  const float* xb = x + b*TC*TL + l;
  float4 acc[16];
  #pragma unroll
  for (int oo=0;oo<16;++oo){ acc[oo].x=0.f; acc[oo].y=0.f; acc[oo].z=0.f; acc[oo].w=0.f; }
  #pragma unroll 4
  for (int c=0;c<64;++c){
    const float4 xv = *(const float4*)(xb + c*TL);
    #pragma unroll
    for (int oo=0;oo<16;++oo){
      const float nv = Np[oo*64 + c];
      acc[oo].x = fmaf(nv, xv.x, acc[oo].x);
      acc[oo].y = fmaf(nv, xv.y, acc[oo].y);
      acc[oo].z = fmaf(nv, xv.z, acc[oo].z);
      acc[oo].w = fmaf(nv, xv.w, acc[oo].w);
    }
  }
  #pragma unroll
  for (int oo=0;oo<16;++oo){
    const float a2v = a2l[w*16+oo], ev = el[w*16+oo];
    float4 r;
    r.x = fmaxf(fmaf(a2v, acc[oo].x, ev), 0.f);
    r.y = fmaxf(fmaf(a2v, acc[oo].y, ev), 0.f);
    r.z = fmaxf(fmaf(a2v, acc[oo].z, ev), 0.f);
    r.w = fmaxf(fmaf(a2v, acc[oo].w, ev), 0.f);
    *(float4*)(out + (b*TC + w*16 + oo)*TL + l) = r;
  }
}

extern "C" void kernel_launch(void* const* d_in, const int* in_sizes, int n_in,
                              void* d_out, int out_size, void* d_ws, size_t ws_size,
                              hipStream_t stream){
  const float* x  = (const float*)d_in[0];
  const float* wk = (const float*)d_in[1];
  const float* wq = (const float*)d_in[2];
  const float* wv = (const float*)d_in[3];
  const float* wc = (const float*)d_in[4];
  const float* g1 = (const float*)d_in[5];
  /* b1 (d_in[6]) provably cancels through BN2 mean-subtraction */
  const float* wl = (const float*)d_in[7];
  const float* g2 = (const float*)d_in[8];
  const float* b2 = (const float*)d_in[9];
  float* out = (float*)d_out;
  float* ws  = (float*)d_ws;

  k1_gram    <<<dim3(16,16), 512, 0, stream>>>(x, ws);
  ka_reduce  <<<dim3(4,16),  256, 0, stream>>>(ws);
  ka2_s1t    <<<dim3(4,16),  256, 0, stream>>>(wq, ws);
  kb1_scores <<<dim3(16,16), 256, 0, stream>>>(wk, ws);
  kb2_v1     <<<dim3(4,16),  256, 0, stream>>>(wv, ws);
  kc_mpart   <<<dim3(4,16),  256, 0, stream>>>(wc, ws);
  kd_stats1  <<<dim3(4,16),  256, 0, stream>>>(ws);
  ke_n_stats2<<<dim3(4,16),  256, 0, stream>>>(wl, g1, ws);
  k3_out     <<<dim3(32,16), 256, 0, stream>>>(x, g2, b2, ws, out);
}

// Round 8
// 113.318 us; speedup vs baseline: 1.6857x; 1.4236x over previous
//
#include <hip/hip_runtime.h>
#include <math.h>

#define TB 16
#define TL 8192
#define TC 64

constexpr float INV_BL = 1.0f / (16.0f * 8192.0f);
constexpr float EPSV = 1e-5f;
constexpr float INV_SQRT_H = 0.17677669529663687f; // 1/sqrt(32)

// workspace offsets (floats) — unchanged
#define WS_G      0        /* [16][64][64] */
#define WS_SX     65536    /* [16][64] */
#define WS_STATS  66560    /* s1[64] d1[64] s2[64] d2[64] */
#define WS_M      66816    /* [16][64][64] */
#define WS_N      132352   /* [16][64][64] */
#define WS_MPART  197888   /* [16][4][4096] -> ends 460032 */
#define WS_PT     460032   /* attn^T [16][256][256] -> ends 1508608 (overlays GPART) */
#define WS_GPART  460032   /* K1 out: [16][16][4096] -> ends 1508608 */
#define WS_SXPART 1508608  /* [16][16][64] -> ends 1524992 */
#define WS_V1     1524992  /* [16][256][64] -> ends 1787136 */
#define WS_S1T    1787136  /* [16][64][256] -> ends 2049280 */

typedef __attribute__((ext_vector_type(8))) short short8v;  // 8 bf16 (4 VGPRs)
typedef __attribute__((ext_vector_type(4))) float f32x4;    // MFMA C/D

__device__ __forceinline__ ushort bf16rne(float f){
  uint u = __float_as_uint(f);
  u += 0x7FFF + ((u >> 16) & 1);
  return (ushort)(u >> 16);
}

// granule-swizzled address (in ushorts): tile [64 ch][128 k] bf16, granule = 8 bf16
__device__ __forceinline__ int fraddr(int ch, int g){
  return ch*128 + 8*(g ^ (ch & 7));
}

// ---------------- K1: Gram partials + row sums (v5: bf16-split MFMA) ----------------
// grid (16 chunk, 16 b), 512 threads = 8 waves. Subtile 64ch x 128l, double-buffered.
// Wave w owns output tiles (ti=w>>1, tj=2*(w&1)) and (ti, 2*(w&1)+1).
__global__ __launch_bounds__(512) void k1_gram(const float* __restrict__ x,
                                               float* __restrict__ ws){
  __shared__ ushort Xh[2][64*128];
  __shared__ ushort Xl[2][64*128];
  const int b = blockIdx.y, chunk = blockIdx.x;
  const int t = threadIdx.x;
  const int lane = t & 63;
  const int w = __builtin_amdgcn_readfirstlane(t >> 6);
  const int ti  = w >> 1;
  const int tj0 = (w & 1) * 2;
  // staging assignment: a=0 -> (ch0, oct0), a=1 -> (ch0+32, oct0)
  const int ch0 = t >> 4, oct0 = t & 15;
  const int ch1 = ch0 + 32;
  const float* xb = x + (size_t)b*TC*TL + (size_t)chunk*512;
  f32x4 acc0 = {0.f,0.f,0.f,0.f}, acc1 = {0.f,0.f,0.f,0.f};
  float sx0 = 0.f, sx1 = 0.f;
  const int wr0 = fraddr(ch0, oct0 ^ (ch0 & 7) ^ (oct0 ^ (ch0 & 7))); (void)wr0; // (clarity noop)
  const int wa0 = ch0*128 + 8*(oct0 ^ (ch0 & 7));
  const int wa1 = ch1*128 + 8*(oct0 ^ (ch1 & 7));
  // ---- prologue: stage subtile 0 into buf 0 ----
  {
    const float4 A0 = *(const float4*)(xb + ch0*TL + oct0*8);
    const float4 A1 = *(const float4*)(xb + ch0*TL + oct0*8 + 4);
    const float4 B0 = *(const float4*)(xb + ch1*TL + oct0*8);
    const float4 B1 = *(const float4*)(xb + ch1*TL + oct0*8 + 4);
    const float fa[8] = {A0.x,A0.y,A0.z,A0.w,A1.x,A1.y,A1.z,A1.w};
    const float fb[8] = {B0.x,B0.y,B0.z,B0.w,B1.x,B1.y,B1.z,B1.w};
    union { short8v v; ushort u[8]; } ha, la, hb, lb;
    #pragma unroll
    for (int i=0;i<8;++i){
      sx0 += fa[i]; sx1 += fb[i];
      const ushort h0 = bf16rne(fa[i]);
      ha.u[i] = h0;
      la.u[i] = bf16rne(fa[i] - __uint_as_float(((uint)h0)<<16));
      const ushort h1 = bf16rne(fb[i]);
      hb.u[i] = h1;
      lb.u[i] = bf16rne(fb[i] - __uint_as_float(((uint)h1)<<16));
    }
    *(short8v*)&Xh[0][wa0] = ha.v;
    *(short8v*)&Xl[0][wa0] = la.v;
    *(short8v*)&Xh[0][wa1] = hb.v;
    *(short8v*)&Xl[0][wa1] = lb.v;
  }
  __syncthreads();
  // ---- main loop over 4 subtiles ----
  const int rA  = ti*16  + (lane & 15);
  const int rB0 = tj0*16 + (lane & 15);
  const int rB1 = rB0 + 16;
  const int gq  = lane >> 4;
  for (int s=0; s<4; ++s){
    const int cur = s & 1;
    float4 A0, A1, B0, B1;
    const bool pf = (s < 3);
    if (pf){
      const int l0 = (s+1)*128;
      A0 = *(const float4*)(xb + ch0*TL + l0 + oct0*8);
      A1 = *(const float4*)(xb + ch0*TL + l0 + oct0*8 + 4);
      B0 = *(const float4*)(xb + ch1*TL + l0 + oct0*8);
      B1 = *(const float4*)(xb + ch1*TL + l0 + oct0*8 + 4);
    }
    // MFMA over current buffer: 4 k-steps of 32
    #pragma unroll
    for (int kk=0; kk<4; ++kk){
      const int g = kk*4 + gq;
      const short8v Ah  = *(const short8v*)&Xh[cur][fraddr(rA,  g)];
      const short8v Al  = *(const short8v*)&Xl[cur][fraddr(rA,  g)];
      const short8v Bh0 = *(const short8v*)&Xh[cur][fraddr(rB0, g)];
      const short8v Bl0 = *(const short8v*)&Xl[cur][fraddr(rB0, g)];
      const short8v Bh1 = *(const short8v*)&Xh[cur][fraddr(rB1, g)];
      const short8v Bl1 = *(const short8v*)&Xl[cur][fraddr(rB1, g)];
      acc0 = __builtin_amdgcn_mfma_f32_16x16x32_bf16(Ah, Bh0, acc0, 0, 0, 0);
      acc0 = __builtin_amdgcn_mfma_f32_16x16x32_bf16(Ah, Bl0, acc0, 0, 0, 0);
      acc0 = __builtin_amdgcn_mfma_f32_16x16x32_bf16(Al, Bh0, acc0, 0, 0, 0);
      acc0 = __builtin_amdgcn_mfma_f32_16x16x32_bf16(Al, Bl0, acc0, 0, 0, 0);
      acc1 = __builtin_amdgcn_mfma_f32_16x16x32_bf16(Ah, Bh1, acc1, 0, 0, 0);
      acc1 = __builtin_amdgcn_mfma_f32_16x16x32_bf16(Ah, Bl1, acc1, 0, 0, 0);
      acc1 = __builtin_amdgcn_mfma_f32_16x16x32_bf16(Al, Bh1, acc1, 0, 0, 0);
      acc1 = __builtin_amdgcn_mfma_f32_16x16x32_bf16(Al, Bl1, acc1, 0, 0, 0);
    }
    if (pf){
      const int nxt = cur ^ 1;
      const float fa[8] = {A0.x,A0.y,A0.z,A0.w,A1.x,A1.y,A1.z,A1.w};
      const float fb[8] = {B0.x,B0.y,B0.z,B0.w,B1.x,B1.y,B1.z,B1.w};
      union { short8v v; ushort u[8]; } ha, la, hb, lb;
      #pragma unroll
      for (int i=0;i<8;++i){
        sx0 += fa[i]; sx1 += fb[i];
        const ushort h0 = bf16rne(fa[i]);
        ha.u[i] = h0;
        la.u[i] = bf16rne(fa[i] - __uint_as_float(((uint)h0)<<16));
        const ushort h1 = bf16rne(fb[i]);
        hb.u[i] = h1;
        lb.u[i] = bf16rne(fb[i] - __uint_as_float(((uint)h1)<<16));
      }
      *(short8v*)&Xh[nxt][wa0] = ha.v;
      *(short8v*)&Xl[nxt][wa0] = la.v;
      *(short8v*)&Xh[nxt][wa1] = hb.v;
      *(short8v*)&Xl[nxt][wa1] = lb.v;
    }
    __syncthreads();
  }
  // ---- write Gram partial: C/D map col=lane&15, row=(lane>>4)*4+r (m89/m91) ----
  float* Gp = ws + WS_GPART + (b*16 + chunk)*4096;
  const int col = lane & 15, rq = lane >> 4;
  #pragma unroll
  for (int r=0;r<4;++r){
    Gp[(ti*16 + rq*4 + r)*64 + tj0*16      + col] = acc0[r];
    Gp[(ti*16 + rq*4 + r)*64 + tj0*16 + 16 + col] = acc1[r];
  }
  // ---- Sx partial: reduce across the 16 lanes sharing each channel ----
  #pragma unroll
  for (int off=1; off<16; off<<=1){
    sx0 += __shfl_xor(sx0, off, 16);
    sx1 += __shfl_xor(sx1, off, 16);
  }
  if (oct0 == 0){
    float* Sp = ws + WS_SXPART + (b*16+chunk)*64;
    Sp[ch0] = sx0;
    Sp[ch1] = sx1;
  }
}

// ---------------- KA: reduce G/Sx partials, zero stats ----------------
__global__ __launch_bounds__(256) void ka_reduce(float* __restrict__ ws){
  const int b = blockIdx.y, ig = blockIdx.x;
  const int t = threadIdx.x;
  const int base = ig*1024;
  float s[4] = {0.f,0.f,0.f,0.f};
  const float* Gp = ws + WS_GPART + b*16*4096 + base;
  #pragma unroll 4
  for (int ch=0; ch<16; ++ch){
    #pragma unroll
    for (int r=0;r<4;++r) s[r] += Gp[ch*4096 + t + 256*r];
  }
  #pragma unroll
  for (int r=0;r<4;++r) ws[WS_G + b*4096 + base + t + 256*r] = s[r];
  if (ig==0){
    if (t<64){
      float sv = 0.f;
      #pragma unroll 4
      for (int ch=0; ch<16; ++ch) sv += ws[WS_SXPART + (b*16+ch)*64 + t];
      ws[WS_SX + b*64 + t] = sv;
    }
    if (b==0) ws[WS_STATS + t] = 0.f;
  }
}

// ---------------- KA2: S1^T = (wq G)^T ----------------
__global__ __launch_bounds__(256) void ka2_s1t(const float* __restrict__ wq,
                                               float* __restrict__ ws){
  __shared__ float Gt[64*68];
  const int b = blockIdx.y, iblk = blockIdx.x;
  const int t = threadIdx.x;
  const float* G = ws + WS_G + b*4096;
  #pragma unroll
  for (int r=0;r<4;++r){
    const int idx = r*1024 + t*4;
    *(float4*)&Gt[(idx>>6)*68 + (idx&63)] = *(const float4*)(G + idx);
  }
  __syncthreads();
  const int il = t>>2, cq = t&3;
  const int i = iblk*64 + il;
  const float* wqr = wq + i*64;
  float4 a0={0,0,0,0}, a1={0,0,0,0}, a2={0,0,0,0}, a3={0,0,0,0};
  #pragma unroll 8
  for (int k=0;k<64;++k){
    const float a = wqr[k];
    const float4 g0 = *(const float4*)&Gt[k*68 + cq*16 + 0];
    const float4 g1 = *(const float4*)&Gt[k*68 + cq*16 + 4];
    const float4 g2 = *(const float4*)&Gt[k*68 + cq*16 + 8];
    const float4 g3 = *(const float4*)&Gt[k*68 + cq*16 + 12];
    a0.x=fmaf(a,g0.x,a0.x); a0.y=fmaf(a,g0.y,a0.y); a0.z=fmaf(a,g0.z,a0.z); a0.w=fmaf(a,g0.w,a0.w);
    a1.x=fmaf(a,g1.x,a1.x); a1.y=fmaf(a,g1.y,a1.y); a1.z=fmaf(a,g1.z,a1.z); a1.w=fmaf(a,g1.w,a1.w);
    a2.x=fmaf(a,g2.x,a2.x); a2.y=fmaf(a,g2.y,a2.y); a2.z=fmaf(a,g2.z,a2.z); a2.w=fmaf(a,g2.w,a2.w);
    a3.x=fmaf(a,g3.x,a3.x); a3.y=fmaf(a,g3.y,a3.y); a3.z=fmaf(a,g3.z,a3.z); a3.w=fmaf(a,g3.w,a3.w);
  }
  float* S1T = ws + WS_S1T + b*16384;
  const int c0 = cq*16;
  S1T[(c0+ 0)*256 + i]=a0.x; S1T[(c0+ 1)*256 + i]=a0.y; S1T[(c0+ 2)*256 + i]=a0.z; S1T[(c0+ 3)*256 + i]=a0.w;
  S1T[(c0+ 4)*256 + i]=a1.x; S1T[(c0+ 5)*256 + i]=a1.y; S1T[(c0+ 6)*256 + i]=a1.z; S1T[(c0+ 7)*256 + i]=a1.w;
  S1T[(c0+ 8)*256 + i]=a2.x; S1T[(c0+ 9)*256 + i]=a2.y; S1T[(c0+10)*256 + i]=a2.z; S1T[(c0+11)*256 + i]=a2.w;
  S1T[(c0+12)*256 + i]=a3.x; S1T[(c0+13)*256 + i]=a3.y; S1T[(c0+14)*256 + i]=a3.z; S1T[(c0+15)*256 + i]=a3.w;
}

// ---------------- KB1: scores + column softmax -> P^T (global) ----------------
__global__ __launch_bounds__(256) void kb1_scores(const float* __restrict__ wk,
                                                  float* __restrict__ ws){
  __shared__ float scl[256*17];
  __shared__ float pstat[256];
  __shared__ float fstat[32];
  const int b = blockIdx.y, jp = blockIdx.x;
  const int j0 = jp*16;
  const int t = threadIdx.x;
  const float* S1Tb = ws + WS_S1T + b*16384;
  float sc[16];
  #pragma unroll
  for (int jj=0;jj<16;++jj) sc[jj]=0.f;
  #pragma unroll 2
  for (int k=0;k<64;++k){
    const float s1 = S1Tb[k*256 + t];
    const float* wkr = wk + j0*64 + k;
    #pragma unroll
    for (int jj=0;jj<16;++jj)
      sc[jj] = fmaf(wkr[jj*64], s1, sc[jj]);
  }
  #pragma unroll
  for (int jj=0;jj<16;++jj) scl[t*17+jj] = sc[jj];
  __syncthreads();
  const int col = t&15, ig = t>>4;
  {
    float m = -3.0e38f;
    #pragma unroll
    for (int q=0;q<16;++q) m = fmaxf(m, scl[(ig*16+q)*17 + col]);
    pstat[ig*16+col] = m;
  }
  __syncthreads();
  if (t<16){
    float m = -3.0e38f;
    #pragma unroll
    for (int q=0;q<16;++q) m = fmaxf(m, pstat[q*16+t]);
    fstat[t] = m;
  }
  __syncthreads();
  {
    const float mj = fstat[col];
    float s = 0.f;
    #pragma unroll
    for (int q=0;q<16;++q) s += __expf(scl[(ig*16+q)*17 + col] - mj);
    pstat[ig*16+col] = s;
  }
  __syncthreads();
  if (t<16){
    float s = 0.f;
    #pragma unroll
    for (int q=0;q<16;++q) s += pstat[q*16+t];
    fstat[16+t] = 1.f/s;
  }
  __syncthreads();
  float* PTb = ws + WS_PT + b*65536;
  #pragma unroll
  for (int jj=0;jj<16;++jj){
    const float p = __expf(sc[jj] - fstat[jj]) * fstat[16+jj];
    PTb[(j0+jj)*256 + t] = p;
  }
}

// ---------------- KB2: V1 = (P wv) * 1/sqrt(H) ----------------
__global__ __launch_bounds__(256) void kb2_v1(const float* __restrict__ wv,
                                              float* __restrict__ ws){
  __shared__ float PTl[64*65];
  const int b = blockIdx.y, iq = blockIdx.x;
  const int t = threadIdx.x;
  const int i = t&63;
  const int cg = __builtin_amdgcn_readfirstlane(t>>6);
  float acc[16];
  #pragma unroll
  for (int cc=0;cc<16;++cc) acc[cc]=0.f;
  const float* PTb = ws + WS_PT + b*65536 + iq*64;
  for (int jc=0;jc<4;++jc){
    __syncthreads();
    #pragma unroll
    for (int r=0;r<16;++r){
      const int e = t + 256*r;
      PTl[(e>>6)*65 + (e&63)] = PTb[(jc*64 + (e>>6))*256 + (e&63)];
    }
    __syncthreads();
    #pragma unroll 4
    for (int jj=0;jj<64;++jj){
      const float p = PTl[jj*65 + i];
      const float* wvr = wv + (jc*64+jj)*64 + cg*16;
      #pragma unroll
      for (int cc=0;cc<16;++cc)
        acc[cc] = fmaf(p, wvr[cc], acc[cc]);
    }
  }
  float* V1o = ws + WS_V1 + b*16384 + (iq*64+i)*64 + cg*16;
  #pragma unroll
  for (int cc=0;cc<16;++cc) V1o[cc] = acc[cc]*INV_SQRT_H;
}

// ---------------- KC: M K-partials = wc-slice @ V1-slice ----------------
__global__ __launch_bounds__(256) void kc_mpart(const float* __restrict__ wc,
                                                float* __restrict__ ws){
  __shared__ float V1l[4096];
  const int b = blockIdx.y, kq = blockIdx.x;
  const int t = threadIdx.x;
  const float* Vsrc = ws + WS_V1 + b*16384 + kq*4096;
  #pragma unroll
  for (int r=0;r<16;++r) V1l[t + 256*r] = Vsrc[t + 256*r];
  __syncthreads();
  const int c = t&63;
  const int og = __builtin_amdgcn_readfirstlane(t>>6);
  float acc[16];
  #pragma unroll
  for (int oo=0;oo<16;++oo) acc[oo]=0.f;
  #pragma unroll 4
  for (int i=0;i<64;++i){
    const float v = V1l[i*64 + c];
    const float* wcr = wc + (og*16)*256 + kq*64 + i;
    #pragma unroll
    for (int oo=0;oo<16;++oo)
      acc[oo] = fmaf(wcr[oo*256], v, acc[oo]);
  }
  float* Mp = ws + WS_MPART + (b*4 + kq)*4096;
  #pragma unroll
  for (int oo=0;oo<16;++oo)
    Mp[(og*16+oo)*64 + c] = acc[oo];
}

// ---------------- KD: M rows + BN1 stats partials ----------------
__global__ __launch_bounds__(256) void kd_stats1(float* __restrict__ ws){
  __shared__ float Msub[16*65];
  __shared__ float Gl[64*67];
  __shared__ float Sxl[64];
  const int b = blockIdx.y, oq = blockIdx.x;
  const int t = threadIdx.x;
  const float* Mp = ws + WS_MPART + b*4*4096 + oq*1024;
  #pragma unroll
  for (int r=0;r<4;++r){
    const int e = t + 256*r;
    const float s = Mp[e] + Mp[4096+e] + Mp[2*4096+e] + Mp[3*4096+e];
    ws[WS_M + b*4096 + oq*1024 + e] = s;
    Msub[(e>>6)*65 + (e&63)] = s;
  }
  #pragma unroll 4
  for (int r=0;r<16;++r){
    const int e = t + 256*r;
    Gl[(e>>6)*67 + (e&63)] = ws[WS_G + b*4096 + e];
  }
  if (t<64) Sxl[t] = ws[WS_SX + b*64 + t];
  __syncthreads();
  const int o = t>>4, q = t&15;
  float d = 0.f;
  #pragma unroll
  for (int kk=0;kk<4;++kk){
    const int k = q*4+kk;
    float s = 0.f;
    #pragma unroll 4
    for (int c=0;c<64;++c) s = fmaf(Gl[k*67+c], Msub[o*65+c], s);
    d = fmaf(Msub[o*65+k], s, d);
  }
  d += __shfl_xor(d, 1, 16);
  d += __shfl_xor(d, 2, 16);
  d += __shfl_xor(d, 4, 16);
  d += __shfl_xor(d, 8, 16);
  if (q==0){
    float s1 = 0.f;
    #pragma unroll 4
    for (int c=0;c<64;++c) s1 = fmaf(Msub[o*65+c], Sxl[c], s1);
    atomicAdd(&ws[WS_STATS + oq*16 + o], s1);
    atomicAdd(&ws[WS_STATS + 64 + oq*16 + o], d);
  }
}

// ---------------- KE: N rows + BN2 stats partials ----------------
__global__ __launch_bounds__(256) void ke_n_stats2(const float* __restrict__ wl,
                                                   const float* __restrict__ g1,
                                                   float* __restrict__ ws){
  __shared__ float Ml[64*65];
  __shared__ float Gl[64*67];
  __shared__ float wls[16*65];
  __shared__ float Nsub[16*65];
  __shared__ float Sxl[64], a1l[64];
  const int b = blockIdx.y, oq = blockIdx.x;
  const int t = threadIdx.x;
  if (t<64){
    const float mean1 = ws[WS_STATS+t]*INV_BL;
    const float var1 = ws[WS_STATS+64+t]*INV_BL - mean1*mean1;
    a1l[t] = g1[t]*rsqrtf(var1 + EPSV);
    Sxl[t] = ws[WS_SX + b*64 + t];
  }
  #pragma unroll 4
  for (int r=0;r<16;++r){
    const int e = t + 256*r;
    Ml[(e>>6)*65 + (e&63)] = ws[WS_M + b*4096 + e];
    Gl[(e>>6)*67 + (e&63)] = ws[WS_G + b*4096 + e];
  }
  __syncthreads();
  #pragma unroll
  for (int r=0;r<4;++r){
    const int e = t + 256*r;
    wls[(e>>6)*65 + (e&63)] = wl[(oq*16 + (e>>6))*64 + (e&63)] * a1l[e&63];
  }
  __syncthreads();
  const int o = t>>4, q = t&15;
  const int row = oq*16 + o;
  {
    float acc[4];
    #pragma unroll
    for (int cc=0;cc<4;++cc) acc[cc]=0.f;
    #pragma unroll 4
    for (int k=0;k<64;++k){
      const float w = wls[o*65 + k];
      #pragma unroll
      for (int cc=0;cc<4;++cc)
        acc[cc] = fmaf(w, Ml[k*65 + q*4 + cc], acc[cc]);
    }
    #pragma unroll
    for (int cc=0;cc<4;++cc){
      const float nv = acc[cc] + wl[row*64 + q*4 + cc];
      ws[WS_N + b*4096 + o*64 + oq*1024 + q*4 + cc] = nv;
      Nsub[o*65 + q*4 + cc] = nv;
    }
  }
  __syncthreads();
  float d = 0.f;
  #pragma unroll
  for (int kk=0;kk<4;++kk){
    const int k = q*4+kk;
    float s = 0.f;
    #pragma unroll 4
    for (int c=0;c<64;++c) s = fmaf(Gl[k*67+c], Nsub[o*65+c], s);
    d = fmaf(Nsub[o*65+k], s, d);
  }
  d += __shfl_xor(d, 1, 16);
  d += __shfl_xor(d, 2, 16);
  d += __shfl_xor(d, 4, 16);
  d += __shfl_xor(d, 8, 16);
  if (q==0){
    float s2 = 0.f;
    #pragma unroll 4
    for (int c=0;c<64;++c) s2 = fmaf(Nsub[o*65+c], Sxl[c], s2);
    atomicAdd(&ws[WS_STATS + 128 + row], s2);
    atomicAdd(&ws[WS_STATS + 192 + row], d);
  }
}

// ---------------- K3: out = relu(a2*(N x) + e) ----------------
__global__ __launch_bounds__(256) void k3_out(const float* __restrict__ x,
                                              const float* __restrict__ g2,
                                              const float* __restrict__ b2,
                                              const float* __restrict__ ws,
                                              float* __restrict__ out){
  __shared__ float a2l[64], el[64];
  const int b = blockIdx.y, lc = blockIdx.x;
  const int t = threadIdx.x;
  if (t<64){
    const float mu = ws[WS_STATS+128+t]*INV_BL;
    const float var2 = ws[WS_STATS+192+t]*INV_BL - mu*mu;
    const float a2 = g2[t]*rsqrtf(var2 + EPSV);
    a2l[t] = a2;
    el[t] = b2[t] - a2*mu;
  }
  __syncthreads();
  const int w = __builtin_amdgcn_readfirstlane(t >> 6);
  const int lane = t & 63;
  const int l = lc*256 + 4*lane;
  const float* Np = ws + WS_N + b*4096 + w*1024;
  const float* xb = x + b*TC*TL + l;
  float4 acc[16];
  #pragma unroll
  for (int oo=0;oo<16;++oo){ acc[oo].x=0.f; acc[oo].y=0.f; acc[oo].z=0.f; acc[oo].w=0.f; }
  #pragma unroll 4
  for (int c=0;c<64;++c){
    const float4 xv = *(const float4*)(xb + c*TL);
    #pragma unroll
    for (int oo=0;oo<16;++oo){
      const float nv = Np[oo*64 + c];
      acc[oo].x = fmaf(nv, xv.x, acc[oo].x);
      acc[oo].y = fmaf(nv, xv.y, acc[oo].y);
      acc[oo].z = fmaf(nv, xv.z, acc[oo].z);
      acc[oo].w = fmaf(nv, xv.w, acc[oo].w);
    }
  }
  #pragma unroll
  for (int oo=0;oo<16;++oo){
    const float a2v = a2l[w*16+oo], ev = el[w*16+oo];
    float4 r;
    r.x = fmaxf(fmaf(a2v, acc[oo].x, ev), 0.f);
    r.y = fmaxf(fmaf(a2v, acc[oo].y, ev), 0.f);
    r.z = fmaxf(fmaf(a2v, acc[oo].z, ev), 0.f);
    r.w = fmaxf(fmaf(a2v, acc[oo].w, ev), 0.f);
    *(float4*)(out + (b*TC + w*16 + oo)*TL + l) = r;
  }
}

extern "C" void kernel_launch(void* const* d_in, const int* in_sizes, int n_in,
                              void* d_out, int out_size, void* d_ws, size_t ws_size,
                              hipStream_t stream){
  const float* x  = (const float*)d_in[0];
  const float* wk = (const float*)d_in[1];
  const float* wq = (const float*)d_in[2];
  const float* wv = (const float*)d_in[3];
  const float* wc = (const float*)d_in[4];
  const float* g1 = (const float*)d_in[5];
  /* b1 (d_in[6]) provably cancels through BN2 mean-subtraction */
  const float* wl = (const float*)d_in[7];
  const float* g2 = (const float*)d_in[8];
  const float* b2 = (const float*)d_in[9];
  float* out = (float*)d_out;
  float* ws  = (float*)d_ws;

  k1_gram    <<<dim3(16,16), 512, 0, stream>>>(x, ws);
  ka_reduce  <<<dim3(4,16),  256, 0, stream>>>(ws);
  ka2_s1t    <<<dim3(4,16),  256, 0, stream>>>(wq, ws);
  kb1_scores <<<dim3(16,16), 256, 0, stream>>>(wk, ws);
  kb2_v1     <<<dim3(4,16),  256, 0, stream>>>(wv, ws);
  kc_mpart   <<<dim3(4,16),  256, 0, stream>>>(wc, ws);
  kd_stats1  <<<dim3(4,16),  256, 0, stream>>>(ws);
  ke_n_stats2<<<dim3(4,16),  256, 0, stream>>>(wl, g1, ws);
  k3_out     <<<dim3(32,16), 256, 0, stream>>>(x, g2, b2, ws, out);
}